// Round 14
// baseline (289.692 us; speedup 1.0000x reference)
//
#include <hip/hip_runtime.h>
#include <hip/hip_bf16.h>

typedef __bf16 bf16x8 __attribute__((ext_vector_type(8)));
typedef float  f32x4  __attribute__((ext_vector_type(4)));

__device__ inline void gld16(const void* g, void* l) {
    __builtin_amdgcn_global_load_lds(
        (const __attribute__((address_space(1))) void*)g,
        (__attribute__((address_space(3))) void*)l, 16, 0, 0);
}

__device__ inline f32x4 mfma16(bf16x8 a, bf16x8 b, f32x4 c) {
    return __builtin_amdgcn_mfma_f32_16x16x32_bf16(a, b, c, 0, 0, 0);
}

__device__ inline unsigned short f2bf(float f) {
    return __builtin_bit_cast(unsigned short, __float2bfloat16(f));
}
__device__ inline float bf2f(unsigned short u) {
    return __bfloat162float(__builtin_bit_cast(__hip_bfloat16, u));
}
__device__ inline unsigned int pack2(float a, float b) {
    return (unsigned int)f2bf(a) | ((unsigned int)f2bf(b) << 16);
}

__device__ inline void storeC(float* p, float v) { *p = v; }
__device__ inline void storeC(__hip_bfloat16* p, float v) { *p = __float2bfloat16(v); }

// ---------------- cast fp32 -> bf16 (x + 4 weights) ----------------
__global__ __launch_bounds__(256) void cast5_kernel(
    const float* __restrict__ x, const float* __restrict__ wq,
    const float* __restrict__ wk, const float* __restrict__ wv,
    const float* __restrict__ wo, __hip_bfloat16* __restrict__ dst_base)
{
    const size_t M1 = 1u << 20;
    const float* src; size_t n, off;
    switch (blockIdx.y) {
        case 0:  src = x;  n = 4 * M1; off = 0;      break;
        case 1:  src = wq; n = M1;     off = 4 * M1; break;
        case 2:  src = wk; n = M1;     off = 5 * M1; break;
        case 3:  src = wv; n = M1;     off = 6 * M1; break;
        default: src = wo; n = M1;     off = 7 * M1; break;
    }
    size_t i = ((size_t)blockIdx.x * 256 + threadIdx.x) * 8;
    if (i >= n) return;
    float4 f0 = *(const float4*)(src + i);
    float4 f1 = *(const float4*)(src + i + 4);
    unsigned short h[8];
    h[0]=f2bf(f0.x); h[1]=f2bf(f0.y); h[2]=f2bf(f0.z); h[3]=f2bf(f0.w);
    h[4]=f2bf(f1.x); h[5]=f2bf(f1.y); h[6]=f2bf(f1.z); h[7]=f2bf(f1.w);
    *(uint4*)(dst_base + off + i) = *(uint4*)h;
}

// ---------------- GEMM: C = A[M,K] * B^T (B stored [N,K]) ----------------
template<typename OUT_T>
__global__ __launch_bounds__(256) void gemm_bt_128(
    const __hip_bfloat16* __restrict__ A,
    const __hip_bfloat16* __restrict__ Ball,   // [z][N,K]
    OUT_T* __restrict__ Call,                  // [z][M,N]
    int M, int N, int K)
{
    __shared__ __align__(16) __hip_bfloat16 As[128 * 32];
    __shared__ __align__(16) __hip_bfloat16 Bs[128 * 32];

    const int z = blockIdx.z;
    const __hip_bfloat16* Bz = Ball + (size_t)z * N * K;
    OUT_T* Cz = Call + (size_t)z * M * N;
    const int m0 = blockIdx.y * 128;
    const int n0 = blockIdx.x * 128;

    const int t = threadIdx.x;
    const int lane = t & 63;
    const int w = t >> 6;
    const int wr = (w >> 1) * 64, wc = (w & 1) * 64;
    const int lr = lane & 15, lk = lane >> 4;

    f32x4 acc[4][4];
    #pragma unroll
    for (int i = 0; i < 4; ++i)
        #pragma unroll
        for (int j = 0; j < 4; ++j)
            acc[i][j] = (f32x4){0.f, 0.f, 0.f, 0.f};

    const int sr = t >> 2;
    const int sc = (t & 3) * 8;

    for (int k0 = 0; k0 < K; k0 += 32) {
        gld16(A  + (size_t)(m0 +      sr) * K + k0 + sc, (char*)As + (size_t)t * 16);
        gld16(A  + (size_t)(m0 + 64 + sr) * K + k0 + sc, (char*)As + 4096 + (size_t)t * 16);
        gld16(Bz + (size_t)(n0 +      sr) * K + k0 + sc, (char*)Bs + (size_t)t * 16);
        gld16(Bz + (size_t)(n0 + 64 + sr) * K + k0 + sc, (char*)Bs + 4096 + (size_t)t * 16);
        asm volatile("s_waitcnt vmcnt(0)" ::: "memory");
        __syncthreads();

        bf16x8 af[4], bfr[4];
        #pragma unroll
        for (int mi = 0; mi < 4; ++mi)
            af[mi] = *(const bf16x8*)&As[(wr + mi * 16 + lr) * 32 + lk * 8];
        #pragma unroll
        for (int ni = 0; ni < 4; ++ni)
            bfr[ni] = *(const bf16x8*)&Bs[(wc + ni * 16 + lr) * 32 + lk * 8];
        #pragma unroll
        for (int mi = 0; mi < 4; ++mi)
            #pragma unroll
            for (int ni = 0; ni < 4; ++ni)
                acc[mi][ni] = mfma16(af[mi], bfr[ni], acc[mi][ni]);
        __syncthreads();
    }

    #pragma unroll
    for (int mi = 0; mi < 4; ++mi) {
        #pragma unroll
        for (int ni = 0; ni < 4; ++ni) {
            const int row = m0 + wr + mi * 16 + lk * 4;
            const int col = n0 + wc + ni * 16 + lr;
            #pragma unroll
            for (int r = 0; r < 4; ++r)
                storeC(&Cz[(size_t)(row + r) * N + col], acc[mi][ni][r]);
        }
    }
}

// ---------------- RoPE: [B,S,H*64] -> [B,H,S,64] ----------------
__global__ __launch_bounds__(256) void rope_kernel(
    const __hip_bfloat16* __restrict__ q_raw,
    const __hip_bfloat16* __restrict__ k_raw,
    __hip_bfloat16* __restrict__ qd,
    __hip_bfloat16* __restrict__ kd,
    const int* __restrict__ tk_pos)
{
    const __hip_bfloat16* src = blockIdx.z ? k_raw : q_raw;
    __hip_bfloat16* dst       = blockIdx.z ? kd : qd;
    int tid = blockIdx.x * 256 + threadIdx.x;
    int i = tid & 31;
    int h = (tid >> 5) & 15;
    int s = (tid >> 9) & 2047;
    int b = tid >> 20;
    float freq = exp2f((float)i * -0.41524101186092029f);
    float ang = (float)tk_pos[s] * freq;
    float sv, cv; sincosf(ang, &sv, &cv);
    unsigned int in2 = *(const unsigned int*)(src + ((size_t)(b * 2048 + s)) * 1024 + h * 64 + 2 * i);
    float x1 = bf2f((unsigned short)(in2 & 0xffffu));
    float x2 = bf2f((unsigned short)(in2 >> 16));
    float oe = x1 * cv - x2 * sv;
    float oo = x1 * sv + x2 * cv;
    unsigned int ob = (unsigned int)f2bf(oe) | ((unsigned int)f2bf(oo) << 16);
    *(unsigned int*)(dst + ((size_t)((b * 16 + h) * 2048 + s)) * 64 + 2 * i) = ob;
}

// ---------------- V transpose: [B,S,H*64] -> [BH,64,S] ----------------
__global__ __launch_bounds__(256) void transpose_v_kernel(
    const __hip_bfloat16* __restrict__ v_raw,
    __hip_bfloat16* __restrict__ vt)
{
    __shared__ __align__(16) __hip_bfloat16 tile[64][80];
    const int s0 = blockIdx.x * 64;
    const int bh = blockIdx.y;
    const int b = bh >> 4, h = bh & 15;
    const int t = threadIdx.x;
    {
        const int si = t >> 2, dg = (t & 3) * 16;
        const __hip_bfloat16* src = v_raw + ((size_t)(b * 2048 + s0 + si)) * 1024 + h * 64 + dg;
        uint4 a0 = *(const uint4*)src;
        uint4 a1 = *(const uint4*)(src + 8);
        *(uint4*)&tile[si][dg] = a0;
        *(uint4*)&tile[si][dg + 8] = a1;
    }
    __syncthreads();
    {
        const int dw = t >> 2, sg = (t & 3) * 16;
        unsigned short tmp[16];
        #pragma unroll
        for (int j = 0; j < 16; ++j)
            tmp[j] = __builtin_bit_cast(unsigned short, tile[sg + j][dw]);
        __hip_bfloat16* dst = vt + ((size_t)bh * 64 + dw) * 2048 + s0 + sg;
        *(uint4*)dst = *(uint4*)tmp;
        *(uint4*)(dst + 8) = *((uint4*)tmp + 1);
    }
}

// ---------------- causal flash attention (swapped QK^T, KVBLK=128, kv-split-2) ----
// 1024 blocks x 256 threads (4 waves). XCD decode: bid&7 -> 4 bh per XCD (L2-local).
// Wave w: pair = xblk*2 + (w&1); half = w>>1 processes kv0 = half*128 step 256.
// Each iteration covers 128 kv as TWO independent 64-kv sub-chains with ONE
// softmax state update -> per-work serial latency halved vs KVBLK=64.
// Halves merge in-block via LDS (exact online-softmax associativity, f32).
__global__ __launch_bounds__(256, 4) void attn_kernel(
    const __hip_bfloat16* __restrict__ q,   // [BH,S,64]
    const __hip_bfloat16* __restrict__ k,   // [BH,S,64]
    const __hip_bfloat16* __restrict__ vt,  // [BH,64,S]
    __hip_bfloat16* __restrict__ o)         // [B,S,1024]
{
    const int S = 2048;
    const float CSCALE = 0.18033688011112042f;   // 0.125 * log2(e)
    __shared__ __align__(16) __hip_bfloat16 Pst[4][16][136];  // P[q][kv0..127], stride 272B
    __shared__ __align__(16) float Mpo[2][64][16];            // partial po
    __shared__ float Mml[2][64][2];                           // partial m,l
    const int bid = blockIdx.x;
    const int xcd = bid & 7;
    const int slot = bid >> 3;              // 0..127
    const int bh = xcd * 4 + (slot >> 5);   // 4 bh per XCD
    const int xblk = slot & 31;             // 0..31
    const int b = bh >> 4, h = bh & 15;
    const int tid = threadIdx.x;
    const int lane = tid & 63;
    const int w = tid >> 6;                 // 0..3
    const int pi = w & 1;                   // pair slot in block
    const int half = w >> 1;                // kv-split half
    const int lr = lane & 15, lk = lane >> 4;
    const int pair = xblk * 2 + pi;         // 0..63

    const __hip_bfloat16* qb = q  + (size_t)bh * S * 64;
    const __hip_bfloat16* kb = k  + (size_t)bh * S * 64 + (size_t)lr * 64 + lk * 8;
    const __hip_bfloat16* vb = vt + (size_t)bh * 64 * S + (size_t)lr * S + lk * 8;

    for (int ti = 0; ti < 2; ++ti) {
        const int qtile = ti ? (127 - pair) : pair;
        const int qw = qtile * 16;

        bf16x8 qf0 = *(const bf16x8*)(qb + (size_t)(qw + lr) * 64 + lk * 8);
        bf16x8 qf1 = *(const bf16x8*)(qb + (size_t)(qw + lr) * 64 + 32 + lk * 8);

        f32x4 po[4];
        #pragma unroll
        for (int dc = 0; dc < 4; ++dc) po[dc] = (f32x4){0.f, 0.f, 0.f, 0.f};
        float mrow = -1e30f, lrow = 0.f;

        for (int kv0 = half * 128; kv0 < qw + 16; kv0 += 256) {
            // ---- QK^T: 8 x 16-kv tiles, all MFMAs independent ----
            f32x4 sc[8];
            #pragma unroll
            for (int t = 0; t < 8; ++t) {
                const __hip_bfloat16* kr = kb + (size_t)(kv0 + 16 * t) * 64;
                f32x4 a = (f32x4){0.f, 0.f, 0.f, 0.f};
                a = mfma16(*(const bf16x8*)kr, qf0, a);
                a = mfma16(*(const bf16x8*)(kr + 32), qf1, a);
                sc[t] = a;
            }
            float s[32];
            #pragma unroll
            for (int t = 0; t < 8; ++t)
                #pragma unroll
                for (int r = 0; r < 4; ++r)
                    s[4 * t + r] = sc[t][r] * CSCALE;
            if (kv0 + 127 > qw) {          // masking needed (wave-uniform)
                #pragma unroll
                for (int t = 0; t < 8; ++t)
                    #pragma unroll
                    for (int r = 0; r < 4; ++r)
                        if (kv0 + 16 * t + lk * 4 + r > qw + lr) s[4 * t + r] = -1e30f;
            }
            // ---- online softmax: ONE state update per 128 kv ----
            float pm = s[0];
            #pragma unroll
            for (int i = 1; i < 32; ++i) pm = fmaxf(pm, s[i]);
            pm = fmaxf(pm, __shfl_xor(pm, 16));
            pm = fmaxf(pm, __shfl_xor(pm, 32));
            float mn = fmaxf(mrow, pm);
            float fac = exp2f(mrow - mn);
            float ps = 0.f;
            #pragma unroll
            for (int i = 0; i < 32; ++i) { float pv = exp2f(s[i] - mn); s[i] = pv; ps += pv; }
            ps += __shfl_xor(ps, 16);
            ps += __shfl_xor(ps, 32);
            lrow = lrow * fac + ps;
            mrow = mn;
            #pragma unroll
            for (int dc = 0; dc < 4; ++dc) {
                f32x4 v = po[dc];
                v[0] *= fac; v[1] *= fac; v[2] *= fac; v[3] *= fac;
                po[dc] = v;
            }
            // ---- P -> LDS (P[q][kv0..127]), read back as B-frags ----
            #pragma unroll
            for (int t = 0; t < 8; ++t) {
                uint2 u;
                u.x = pack2(s[4 * t], s[4 * t + 1]);
                u.y = pack2(s[4 * t + 2], s[4 * t + 3]);
                *(uint2*)&Pst[w][lr][16 * t + 4 * lk] = u;
            }
            bf16x8 pf[4];
            #pragma unroll
            for (int c = 0; c < 4; ++c)
                pf[c] = *(const bf16x8*)&Pst[w][lr][32 * c + lk * 8];
            // ---- PV: 16 independent MFMAs ----
            #pragma unroll
            for (int dc = 0; dc < 4; ++dc) {
                const __hip_bfloat16* vr = vb + (size_t)(dc * 16) * S + kv0;
                #pragma unroll
                for (int c = 0; c < 4; ++c)
                    po[dc] = mfma16(*(const bf16x8*)(vr + 32 * c), pf[c], po[dc]);
            }
        }

        // ---- merge halves: half1 publishes partial, half0 merges + stores ----
        if (half == 1) {
            #pragma unroll
            for (int dc = 0; dc < 4; ++dc)
                #pragma unroll
                for (int r = 0; r < 4; ++r)
                    Mpo[pi][lane][dc * 4 + r] = po[dc][r];
            Mml[pi][lane][0] = mrow;
            Mml[pi][lane][1] = lrow;
        }
        __syncthreads();
        if (half == 0) {
            float m1 = Mml[pi][lane][0];
            float l1 = Mml[pi][lane][1];
            float mm = fmaxf(mrow, m1);
            float f0 = exp2f(mrow - mm);
            float f1 = exp2f(m1 - mm);
            float inv = 1.0f / (lrow * f0 + l1 * f1);
            #pragma unroll
            for (int dc = 0; dc < 4; ++dc) {
                uint2 u;
                float v0 = (po[dc][0] * f0 + Mpo[pi][lane][dc * 4 + 0] * f1) * inv;
                float v1 = (po[dc][1] * f0 + Mpo[pi][lane][dc * 4 + 1] * f1) * inv;
                float v2 = (po[dc][2] * f0 + Mpo[pi][lane][dc * 4 + 2] * f1) * inv;
                float v3 = (po[dc][3] * f0 + Mpo[pi][lane][dc * 4 + 3] * f1) * inv;
                u.x = pack2(v0, v1);
                u.y = pack2(v2, v3);
                *(uint2*)&Pst[w][lr][dc * 16 + 4 * lk] = u;
            }
            const int qrow = lane >> 2;          // 0..15
            const int dseg = (lane & 3) * 16;    // 0,16,32,48
            uint4 ov0 = *(const uint4*)&Pst[w][qrow][dseg];
            uint4 ov1 = *(const uint4*)&Pst[w][qrow][dseg + 8];
            __hip_bfloat16* dst = o + ((size_t)(b * S + qw + qrow)) * 1024 + h * 64 + dseg;
            *(uint4*)dst = ov0;
            *(uint4*)(dst + 8) = ov1;
        }
        __syncthreads();
    }
}

// ---------------- launch ----------------
extern "C" void kernel_launch(void* const* d_in, const int* in_sizes, int n_in,
                              void* d_out, int out_size, void* d_ws, size_t ws_size,
                              hipStream_t stream)
{
    const float* x  = (const float*)d_in[0];
    const int* tkp  = (const int*)d_in[1];
    const float* wq = (const float*)d_in[2];
    const float* wk = (const float*)d_in[3];
    const float* wv = (const float*)d_in[4];
    const float* wo = (const float*)d_in[5];
    float* out = (float*)d_out;

    const size_t M1 = 1u << 20;
    __hip_bfloat16* wsb  = (__hip_bfloat16*)d_ws;
    __hip_bfloat16* xb   = wsb;              // 4M elems
    __hip_bfloat16* wb   = wsb + 4 * M1;     // 4M   (wq,wk,wv,wo bf16)
    __hip_bfloat16* qkvr = wsb + 8 * M1;     // 12M  (q_raw,k_raw,v_raw)
    __hip_bfloat16* qd   = wsb + 20 * M1;    // 4M   [BH,S,64]
    __hip_bfloat16* kd   = wsb + 24 * M1;    // 4M
    __hip_bfloat16* vtb  = wsb + 28 * M1;    // 4M   [BH,64,S]
    __hip_bfloat16* od   = qkvr;             // alias q_raw (free after rope)

    cast5_kernel<<<dim3(2048, 5, 1), 256, 0, stream>>>(x, wq, wk, wv, wo, wsb);
    gemm_bt_128<__hip_bfloat16><<<dim3(8, 32, 3), 256, 0, stream>>>(
        xb, wb, qkvr, 4096, 1024, 1024);
    rope_kernel<<<dim3(8192, 1, 2), 256, 0, stream>>>(
        qkvr, qkvr + 4 * M1, qd, kd, tkp);
    transpose_v_kernel<<<dim3(32, 32, 1), 256, 0, stream>>>(qkvr + 8 * M1, vtb);
    attn_kernel<<<dim3(1024, 1, 1), 256, 0, stream>>>(qd, kd, vtb, od);
    gemm_bt_128<float><<<dim3(8, 32, 1), 256, 0, stream>>>(
        od, wb + 3 * M1, out, 4096, 1024, 1024);
}

// Round 15
// 222.646 us; speedup vs baseline: 1.3011x; 1.3011x over previous
//
#include <hip/hip_runtime.h>
#include <hip/hip_bf16.h>

typedef __bf16 bf16x8 __attribute__((ext_vector_type(8)));
typedef float  f32x4  __attribute__((ext_vector_type(4)));

__device__ inline void gld16(const void* g, void* l) {
    __builtin_amdgcn_global_load_lds(
        (const __attribute__((address_space(1))) void*)g,
        (__attribute__((address_space(3))) void*)l, 16, 0, 0);
}

__device__ inline f32x4 mfma16(bf16x8 a, bf16x8 b, f32x4 c) {
    return __builtin_amdgcn_mfma_f32_16x16x32_bf16(a, b, c, 0, 0, 0);
}

__device__ inline unsigned short f2bf(float f) {
    return __builtin_bit_cast(unsigned short, __float2bfloat16(f));
}
__device__ inline float bf2f(unsigned short u) {
    return __bfloat162float(__builtin_bit_cast(__hip_bfloat16, u));
}
__device__ inline unsigned int pack2(float a, float b) {
    return (unsigned int)f2bf(a) | ((unsigned int)f2bf(b) << 16);
}

__device__ inline void storeC(float* p, float v) { *p = v; }
__device__ inline void storeC(__hip_bfloat16* p, float v) { *p = __float2bfloat16(v); }

// ---------------- cast fp32 -> bf16 (x + 4 weights) ----------------
__global__ __launch_bounds__(256) void cast5_kernel(
    const float* __restrict__ x, const float* __restrict__ wq,
    const float* __restrict__ wk, const float* __restrict__ wv,
    const float* __restrict__ wo, __hip_bfloat16* __restrict__ dst_base)
{
    const size_t M1 = 1u << 20;
    const float* src; size_t n, off;
    switch (blockIdx.y) {
        case 0:  src = x;  n = 4 * M1; off = 0;      break;
        case 1:  src = wq; n = M1;     off = 4 * M1; break;
        case 2:  src = wk; n = M1;     off = 5 * M1; break;
        case 3:  src = wv; n = M1;     off = 6 * M1; break;
        default: src = wo; n = M1;     off = 7 * M1; break;
    }
    size_t i = ((size_t)blockIdx.x * 256 + threadIdx.x) * 8;
    if (i >= n) return;
    float4 f0 = *(const float4*)(src + i);
    float4 f1 = *(const float4*)(src + i + 4);
    unsigned short h[8];
    h[0]=f2bf(f0.x); h[1]=f2bf(f0.y); h[2]=f2bf(f0.z); h[3]=f2bf(f0.w);
    h[4]=f2bf(f1.x); h[5]=f2bf(f1.y); h[6]=f2bf(f1.z); h[7]=f2bf(f1.w);
    *(uint4*)(dst_base + off + i) = *(uint4*)h;
}

// ---------------- GEMM: C = A[M,K] * B^T (B stored [N,K]) ----------------
template<typename OUT_T>
__global__ __launch_bounds__(256) void gemm_bt_128(
    const __hip_bfloat16* __restrict__ A,
    const __hip_bfloat16* __restrict__ Ball,   // [z][N,K]
    OUT_T* __restrict__ Call,                  // [z][M,N]
    int M, int N, int K)
{
    __shared__ __align__(16) __hip_bfloat16 As[128 * 32];
    __shared__ __align__(16) __hip_bfloat16 Bs[128 * 32];

    const int z = blockIdx.z;
    const __hip_bfloat16* Bz = Ball + (size_t)z * N * K;
    OUT_T* Cz = Call + (size_t)z * M * N;
    const int m0 = blockIdx.y * 128;
    const int n0 = blockIdx.x * 128;

    const int t = threadIdx.x;
    const int lane = t & 63;
    const int w = t >> 6;
    const int wr = (w >> 1) * 64, wc = (w & 1) * 64;
    const int lr = lane & 15, lk = lane >> 4;

    f32x4 acc[4][4];
    #pragma unroll
    for (int i = 0; i < 4; ++i)
        #pragma unroll
        for (int j = 0; j < 4; ++j)
            acc[i][j] = (f32x4){0.f, 0.f, 0.f, 0.f};

    const int sr = t >> 2;
    const int sc = (t & 3) * 8;

    for (int k0 = 0; k0 < K; k0 += 32) {
        gld16(A  + (size_t)(m0 +      sr) * K + k0 + sc, (char*)As + (size_t)t * 16);
        gld16(A  + (size_t)(m0 + 64 + sr) * K + k0 + sc, (char*)As + 4096 + (size_t)t * 16);
        gld16(Bz + (size_t)(n0 +      sr) * K + k0 + sc, (char*)Bs + (size_t)t * 16);
        gld16(Bz + (size_t)(n0 + 64 + sr) * K + k0 + sc, (char*)Bs + 4096 + (size_t)t * 16);
        asm volatile("s_waitcnt vmcnt(0)" ::: "memory");
        __syncthreads();

        bf16x8 af[4], bfr[4];
        #pragma unroll
        for (int mi = 0; mi < 4; ++mi)
            af[mi] = *(const bf16x8*)&As[(wr + mi * 16 + lr) * 32 + lk * 8];
        #pragma unroll
        for (int ni = 0; ni < 4; ++ni)
            bfr[ni] = *(const bf16x8*)&Bs[(wc + ni * 16 + lr) * 32 + lk * 8];
        #pragma unroll
        for (int mi = 0; mi < 4; ++mi)
            #pragma unroll
            for (int ni = 0; ni < 4; ++ni)
                acc[mi][ni] = mfma16(af[mi], bfr[ni], acc[mi][ni]);
        __syncthreads();
    }

    #pragma unroll
    for (int mi = 0; mi < 4; ++mi) {
        #pragma unroll
        for (int ni = 0; ni < 4; ++ni) {
            const int row = m0 + wr + mi * 16 + lk * 4;
            const int col = n0 + wc + ni * 16 + lr;
            #pragma unroll
            for (int r = 0; r < 4; ++r)
                storeC(&Cz[(size_t)(row + r) * N + col], acc[mi][ni][r]);
        }
    }
}

// ---------------- RoPE: [B,S,H*64] -> [B,H,S,64] ----------------
__global__ __launch_bounds__(256) void rope_kernel(
    const __hip_bfloat16* __restrict__ q_raw,
    const __hip_bfloat16* __restrict__ k_raw,
    __hip_bfloat16* __restrict__ qd,
    __hip_bfloat16* __restrict__ kd,
    const int* __restrict__ tk_pos)
{
    const __hip_bfloat16* src = blockIdx.z ? k_raw : q_raw;
    __hip_bfloat16* dst       = blockIdx.z ? kd : qd;
    int tid = blockIdx.x * 256 + threadIdx.x;
    int i = tid & 31;
    int h = (tid >> 5) & 15;
    int s = (tid >> 9) & 2047;
    int b = tid >> 20;
    float freq = exp2f((float)i * -0.41524101186092029f);
    float ang = (float)tk_pos[s] * freq;
    float sv, cv; sincosf(ang, &sv, &cv);
    unsigned int in2 = *(const unsigned int*)(src + ((size_t)(b * 2048 + s)) * 1024 + h * 64 + 2 * i);
    float x1 = bf2f((unsigned short)(in2 & 0xffffu));
    float x2 = bf2f((unsigned short)(in2 >> 16));
    float oe = x1 * cv - x2 * sv;
    float oo = x1 * sv + x2 * cv;
    unsigned int ob = (unsigned int)f2bf(oe) | ((unsigned int)f2bf(oo) << 16);
    *(unsigned int*)(dst + ((size_t)((b * 16 + h) * 2048 + s)) * 64 + 2 * i) = ob;
}

// ---------------- V transpose: [B,S,H*64] -> [BH,64,S] ----------------
__global__ __launch_bounds__(256) void transpose_v_kernel(
    const __hip_bfloat16* __restrict__ v_raw,
    __hip_bfloat16* __restrict__ vt)
{
    __shared__ __align__(16) __hip_bfloat16 tile[64][80];
    const int s0 = blockIdx.x * 64;
    const int bh = blockIdx.y;
    const int b = bh >> 4, h = bh & 15;
    const int t = threadIdx.x;
    {
        const int si = t >> 2, dg = (t & 3) * 16;
        const __hip_bfloat16* src = v_raw + ((size_t)(b * 2048 + s0 + si)) * 1024 + h * 64 + dg;
        uint4 a0 = *(const uint4*)src;
        uint4 a1 = *(const uint4*)(src + 8);
        *(uint4*)&tile[si][dg] = a0;
        *(uint4*)&tile[si][dg + 8] = a1;
    }
    __syncthreads();
    {
        const int dw = t >> 2, sg = (t & 3) * 16;
        unsigned short tmp[16];
        #pragma unroll
        for (int j = 0; j < 16; ++j)
            tmp[j] = __builtin_bit_cast(unsigned short, tile[sg + j][dw]);
        __hip_bfloat16* dst = vt + ((size_t)bh * 64 + dw) * 2048 + s0 + sg;
        *(uint4*)dst = *(uint4*)tmp;
        *(uint4*)(dst + 8) = *((uint4*)tmp + 1);
    }
}

// ---------------- causal flash attention (LDS-staged K/V, double-buffered) ------
// 512 blocks x 256 threads (4 waves). XCD decode: bid&7 -> 4 bh per XCD.
// Block owns 64 q-rows (wave w: rows qw+16w..+16). Causal balance: passes over
// q-blocks p and 31-p (33 kv-tiles total, equal for all blocks).
// Per kv-tile (64 kv): K[64][64] and V^T[64][64] staged into LDS by all 256
// threads via global_load_lds (16B), double-buffered: issue stage(t+1), compute
// tile t from LDS, vmcnt(0)+barrier, swap. XOR-swizzle (chunk ^= row&7) applied
// on the GLOBAL SOURCE (LDS dest stays linear) and on ds_read addresses ->
// 2-way banks (free). Cuts per-CU VMEM requests 8x vs per-wave global loads.
__global__ __launch_bounds__(256) void attn_kernel(
    const __hip_bfloat16* __restrict__ q,   // [BH,S,64]
    const __hip_bfloat16* __restrict__ k,   // [BH,S,64]
    const __hip_bfloat16* __restrict__ vt,  // [BH,64,S]
    __hip_bfloat16* __restrict__ o)         // [B,S,1024]
{
    const int S = 2048;
    const float CSCALE = 0.18033688011112042f;   // 0.125 * log2(e)
    __shared__ __align__(16) __hip_bfloat16 Kbuf[2][64 * 64];
    __shared__ __align__(16) __hip_bfloat16 Vbuf[2][64 * 64];
    __shared__ __align__(16) __hip_bfloat16 Pst[4][16][72];  // stride 144B

    const int bid = blockIdx.x;             // 0..511
    const int xcd = bid & 7;
    const int slot = bid >> 3;              // 0..63
    const int bh = xcd * 4 + (slot >> 4);   // 4 bh per XCD
    const int pblk = slot & 15;             // 0..15 -> q-blocks pblk, 31-pblk
    const int b = bh >> 4, h = bh & 15;
    const int t = threadIdx.x;
    const int lane = t & 63;
    const int w = t >> 6;                   // 0..3
    const int lr = lane & 15, lk = lane >> 4;

    const __hip_bfloat16* qb = q  + (size_t)bh * S * 64;
    const __hip_bfloat16* kb = k  + (size_t)bh * S * 64;
    const __hip_bfloat16* vb = vt + (size_t)bh * 64 * S;

    // staging coords: thread t covers (row sr + 32j, 16B chunk sc), source
    // chunk XOR-swizzled so that a linear LDS write + swizzled read is bank-free
    const int sr = t >> 3;                  // 0..31
    const int sc = t & 7;                   // chunk
    const int swz = (sc ^ (sr & 7)) * 8;    // element offset within 64-elem row

    // read-side swizzled byte offsets (row & 7 == lr & 7 for all our reads)
    const int ck0 = ((lk) ^ (lr & 7)) * 16;      // chunks 0-3 region
    const int ck1 = ((4 + lk) ^ (lr & 7)) * 16;  // chunks 4-7 region

    for (int ti = 0; ti < 2; ++ti) {
        const int qt = ti ? (31 - pblk) : pblk;
        const int qw = qt * 64;
        const int qww = qw + w * 16;        // wave's q-row base
        const int nt = qt + 1;              // kv tiles of 64

        // stage tile 0 into buf 0
        #pragma unroll
        for (int j = 0; j < 2; ++j) {
            gld16(kb + (size_t)(j * 32 + sr) * 64 + swz,
                  (char*)&Kbuf[0][0] + j * 4096 + t * 16);
            gld16(vb + (size_t)(j * 32 + sr) * S + swz,
                  (char*)&Vbuf[0][0] + j * 4096 + t * 16);
        }
        bf16x8 qf0 = *(const bf16x8*)(qb + (size_t)(qww + lr) * 64 + lk * 8);
        bf16x8 qf1 = *(const bf16x8*)(qb + (size_t)(qww + lr) * 64 + 32 + lk * 8);

        f32x4 po[4];
        #pragma unroll
        for (int dc = 0; dc < 4; ++dc) po[dc] = (f32x4){0.f, 0.f, 0.f, 0.f};
        float mrow = -1e30f, lrow = 0.f;

        asm volatile("s_waitcnt vmcnt(0)" ::: "memory");
        __syncthreads();

        int cur = 0;
        for (int tile = 0; tile < nt; ++tile) {
            const int kv0 = tile * 64;
            if (tile + 1 < nt) {            // issue next-tile staging (async)
                const int kn = kv0 + 64;
                #pragma unroll
                for (int j = 0; j < 2; ++j) {
                    gld16(kb + (size_t)(kn + j * 32 + sr) * 64 + swz,
                          (char*)&Kbuf[cur ^ 1][0] + j * 4096 + t * 16);
                    gld16(vb + (size_t)(j * 32 + sr) * S + kn + swz,
                          (char*)&Vbuf[cur ^ 1][0] + j * 4096 + t * 16);
                }
            }
            // ---- QK^T from LDS (swapped: rows=kv, cols=q) ----
            f32x4 sc4[4];
            #pragma unroll
            for (int tt = 0; tt < 4; ++tt) {
                const char* krow = (const char*)&Kbuf[cur][0] + (16 * tt + lr) * 128;
                f32x4 a = (f32x4){0.f, 0.f, 0.f, 0.f};
                a = mfma16(*(const bf16x8*)(krow + ck0), qf0, a);
                a = mfma16(*(const bf16x8*)(krow + ck1), qf1, a);
                sc4[tt] = a;
            }
            float s[16];
            #pragma unroll
            for (int tt = 0; tt < 4; ++tt)
                #pragma unroll
                for (int r = 0; r < 4; ++r)
                    s[4 * tt + r] = sc4[tt][r] * CSCALE;
            if (kv0 + 63 > qww) {           // diagonal region (wave-uniform)
                #pragma unroll
                for (int tt = 0; tt < 4; ++tt)
                    #pragma unroll
                    for (int r = 0; r < 4; ++r)
                        if (kv0 + 16 * tt + lk * 4 + r > qww + lr) s[4 * tt + r] = -1e30f;
            }
            // ---- online softmax (per-lane scalar state) ----
            float pm = s[0];
            #pragma unroll
            for (int i = 1; i < 16; ++i) pm = fmaxf(pm, s[i]);
            pm = fmaxf(pm, __shfl_xor(pm, 16));
            pm = fmaxf(pm, __shfl_xor(pm, 32));
            float mn = fmaxf(mrow, pm);
            float fac = exp2f(mrow - mn);
            float ps = 0.f;
            #pragma unroll
            for (int i = 0; i < 16; ++i) { float pv = exp2f(s[i] - mn); s[i] = pv; ps += pv; }
            ps += __shfl_xor(ps, 16);
            ps += __shfl_xor(ps, 32);
            lrow = lrow * fac + ps;
            mrow = mn;
            #pragma unroll
            for (int dc = 0; dc < 4; ++dc) {
                f32x4 v = po[dc];
                v[0] *= fac; v[1] *= fac; v[2] *= fac; v[3] *= fac;
                po[dc] = v;
            }
            // ---- P -> per-wave LDS, read back as B-frags ----
            #pragma unroll
            for (int tt = 0; tt < 4; ++tt) {
                uint2 u;
                u.x = pack2(s[4 * tt], s[4 * tt + 1]);
                u.y = pack2(s[4 * tt + 2], s[4 * tt + 3]);
                *(uint2*)&Pst[w][lr][16 * tt + 4 * lk] = u;
            }
            bf16x8 pf0 = *(const bf16x8*)&Pst[w][lr][lk * 8];
            bf16x8 pf1 = *(const bf16x8*)&Pst[w][lr][32 + lk * 8];
            // ---- PV from LDS: out^T[d][q] ----
            #pragma unroll
            for (int dc = 0; dc < 4; ++dc) {
                const char* vrow = (const char*)&Vbuf[cur][0] + (dc * 16 + lr) * 128;
                po[dc] = mfma16(*(const bf16x8*)(vrow + ck0), pf0, po[dc]);
                po[dc] = mfma16(*(const bf16x8*)(vrow + ck1), pf1, po[dc]);
            }
            asm volatile("s_waitcnt vmcnt(0)" ::: "memory");
            __syncthreads();
            cur ^= 1;
        }

        // ---- epilogue: normalize, transpose via Pst, coalesced stores ----
        float inv = 1.0f / lrow;
        #pragma unroll
        for (int dc = 0; dc < 4; ++dc) {
            uint2 u;
            u.x = pack2(po[dc][0] * inv, po[dc][1] * inv);
            u.y = pack2(po[dc][2] * inv, po[dc][3] * inv);
            *(uint2*)&Pst[w][lr][dc * 16 + 4 * lk] = u;
        }
        const int qrow = lane >> 2;          // 0..15
        const int dseg = (lane & 3) * 16;    // 0,16,32,48
        uint4 ov0 = *(const uint4*)&Pst[w][qrow][dseg];
        uint4 ov1 = *(const uint4*)&Pst[w][qrow][dseg + 8];
        __hip_bfloat16* dst = o + ((size_t)(b * S + qww + qrow)) * 1024 + h * 64 + dseg;
        *(uint4*)dst = ov0;
        *(uint4*)(dst + 8) = ov1;
        __syncthreads();   // protect K/V bufs before next pass restages
    }
}

// ---------------- launch ----------------
extern "C" void kernel_launch(void* const* d_in, const int* in_sizes, int n_in,
                              void* d_out, int out_size, void* d_ws, size_t ws_size,
                              hipStream_t stream)
{
    const float* x  = (const float*)d_in[0];
    const int* tkp  = (const int*)d_in[1];
    const float* wq = (const float*)d_in[2];
    const float* wk = (const float*)d_in[3];
    const float* wv = (const float*)d_in[4];
    const float* wo = (const float*)d_in[5];
    float* out = (float*)d_out;

    const size_t M1 = 1u << 20;
    __hip_bfloat16* wsb  = (__hip_bfloat16*)d_ws;
    __hip_bfloat16* xb   = wsb;              // 4M elems
    __hip_bfloat16* wb   = wsb + 4 * M1;     // 4M   (wq,wk,wv,wo bf16)
    __hip_bfloat16* qkvr = wsb + 8 * M1;     // 12M  (q_raw,k_raw,v_raw)
    __hip_bfloat16* qd   = wsb + 20 * M1;    // 4M   [BH,S,64]
    __hip_bfloat16* kd   = wsb + 24 * M1;    // 4M
    __hip_bfloat16* vtb  = wsb + 28 * M1;    // 4M   [BH,64,S]
    __hip_bfloat16* od   = qkvr;             // alias q_raw (free after rope)

    cast5_kernel<<<dim3(2048, 5, 1), 256, 0, stream>>>(x, wq, wk, wv, wo, wsb);
    gemm_bt_128<__hip_bfloat16><<<dim3(8, 32, 3), 256, 0, stream>>>(
        xb, wb, qkvr, 4096, 1024, 1024);
    rope_kernel<<<dim3(8192, 1, 2), 256, 0, stream>>>(
        qkvr, qkvr + 4 * M1, qd, kd, tkp);
    transpose_v_kernel<<<dim3(32, 32, 1), 256, 0, stream>>>(qkvr + 8 * M1, vtb);
    attn_kernel<<<dim3(512, 1, 1), 256, 0, stream>>>(qd, kd, vtb, od);
    gemm_bt_128<float><<<dim3(8, 32, 1), 256, 0, stream>>>(
        od, wb + 3 * M1, out, 4096, 1024, 1024);
}